// Round 29
// baseline (109.462 us; speedup 1.0000x reference)
//
#include <hip/hip_runtime.h>

// VQ-VAE VectorQuantizer fwd. K=1024, E=64, N=T*B=65536.
// 2-tier argmin: 3-term bf16-split MFMA (GAP1=6e-6) -> fp64 exact.
// R29: block-shared LDS staging for the codebook stream. R15-R28 plateau
// (argmin 46-49us): per-wave private K-quarter => b-stream re-read 4x
// (655MB via L2 ~ 19-25us floor + latency). Now all 4 waves scan ALL 64
// tiles from a 2-deep LDS dbuf (global_load_lds w16, 8KB padded records,
// 2 loads/wave/tile, uniform vmcnt(2), RAW s_barrier -- __syncthreads'
// vmcnt(0) drain killed R12's pipeline). L2 fetch 655->262MB; conversion
// once/row (R12's 4x dup removed); wave finalizes its own 32 rows (no
// cross-wave merge). LDS 50KB -> 3 blocks/CU.
// Scores t = ||c||^2 - 2 x.c; codebook pre-scaled by -2, ||c||^2 in C-init.
// MFMA: A = codebook frag, B = x frag -> D(lane l, reg r) =
// score(code = t*16 + (l>>4)*4 + r, row = base + (l&15)).

#define KC 1024
#define ED 64
#define NR 65536
#define NE (NR * ED)
#define GAP1 6e-6f

typedef __attribute__((ext_vector_type(8))) short short8;
typedef __attribute__((ext_vector_type(4))) float f32x4;

__device__ __forceinline__ unsigned short bf16rne(float f) {
    unsigned u = __builtin_bit_cast(unsigned, f);
    return (unsigned short)((u + 0x7fffu + ((u >> 16) & 1u)) >> 16);
}
__device__ __forceinline__ float bf16tof(unsigned short h) {
    return __builtin_bit_cast(float, (unsigned)h << 16);
}

#define GLOAD_LDS16(GSRC, LDST) \
    __builtin_amdgcn_global_load_lds( \
        (const __attribute__((address_space(1))) void*)(GSRC), \
        (__attribute__((address_space(3))) void*)(LDST), 16, 0, 0)

// Pack 8KB-padded tile records (stride 512 short8) + zero counters.
// Record t: j=0,1 = ch (hi bf16 of -2*c) for e in [0,32),[32,64); j=2,3 =
// cl (lo residual) at j*64; elem (g=l>>4,r) <-> e = (j&1)*32 + g*8 + r
// (same bijection as x frags); chunk 4 (off 256): f32x4 ||c||^2 (reg r <->
// code t*16+(l>>4)*4+r) bitcast short8; chunks 5-7: pad (staged, unread).
__global__ __launch_bounds__(256) void k_pack(const float* __restrict__ cb,
        short8* __restrict__ cbt, unsigned* __restrict__ counts,
        unsigned* __restrict__ flagcnt) {
    const int u = blockIdx.x * 256 + threadIdx.x;
    if (u < 1024) counts[u] = 0u;
    if (u == 1024) *flagcnt = 0u;
    if (u >= 64 * 5 * 64) return;
    const int t = u / 320, rem = u % 320, j = rem / 64, l = rem % 64;
    const int g = l >> 4;
    const int w = t * 512 + (j < 4 ? j * 64 : 256) + l;
    if (j < 4) {
        const int code = t * 16 + (l & 15);
        const float* c = cb + (size_t)code * ED;
        const bool lo = (j >= 2);
        short8 o;
#pragma unroll
        for (int r = 0; r < 8; ++r) {
            const int e = (j & 1) * 32 + g * 8 + r;
            const float m2 = -2.f * c[e];
            const unsigned short h = bf16rne(m2);
            o[r] = lo ? (short)bf16rne(m2 - bf16tof(h)) : (short)h;
        }
        cbt[w] = o;
    } else {
        f32x4 o;
#pragma unroll
        for (int r = 0; r < 4; ++r) {
            const float4* c4 = (const float4*)(cb + (size_t)(t * 16 + g * 4 + r) * ED);
            float s0 = 0.f, s1 = 0.f, s2 = 0.f, s3 = 0.f;
#pragma unroll
            for (int i = 0; i < 16; ++i) {
                const float4 c = c4[i];
                s0 = fmaf(c.x, c.x, s0); s1 = fmaf(c.y, c.y, s1);
                s2 = fmaf(c.z, c.z, s2); s3 = fmaf(c.w, c.w, s3);
            }
            o[r] = (s0 + s1) + (s2 + s3);
        }
        cbt[w] = __builtin_bit_cast(short8, o);
    }
}

// 512 blocks x 256 thr (4 waves), 128 rows/block (32/wave), 3 blocks/CU.
// Phase 1: convert x once -> bf16 hi/lo frags in LDS + rx2 (LDS atomic).
// Tile loop (t=0..63): stage tile t+1 via global_load_lds into dbuf
// (2 loads/wave, uniform), vmcnt(2), raw barrier, ds_read 5 records,
// 12 MFMA + min-track, raw barrier. Wave finalizes its own 32 rows
// (idx/fidx/counts/flag/SSE). Phase 4: cooperative qout gather.
__global__ __launch_bounds__(256) void k_argmin(
        const float* __restrict__ in, const short8* __restrict__ cbt,
        const float* __restrict__ cb, int* __restrict__ idx,
        float* __restrict__ qout, unsigned* __restrict__ counts,
        unsigned* __restrict__ flagcnt, unsigned* __restrict__ flaglist,
        double* __restrict__ pblk) {
    __shared__ short8 xs[4][8][64];               // 32 KB
    __shared__ short8 lbuf[2][512];               // 16 KB
    __shared__ float  rx2s[128];                  // 512 B
    __shared__ int    fidx[128];                  // 512 B

    const int tid = threadIdx.x;
    const int l = tid & 63;
    const int wid = tid >> 6;                     // 0..3
    const int g = l >> 4;
    const int rowBase = blockIdx.x * 128;

    if (tid < 128) rx2s[tid] = 0.f;
    __syncthreads();

    // Prologue: stage tile 0 (chunks wid, wid+4; 2 loads/wave, uniform).
    GLOAD_LDS16(cbt + (size_t)0 * 512 + wid * 64 + l, &lbuf[0][wid * 64]);
    GLOAD_LDS16(cbt + (size_t)0 * 512 + (wid + 4) * 64 + l, &lbuf[0][(wid + 4) * 64]);

    // Phase 1: 1024 (row, oct) tasks over 256 threads (4 each). Overlaps
    // the prologue DMA. task -> row = task&127, ob = task>>7.
#pragma unroll
    for (int c = 0; c < 4; ++c) {
        const int task = tid + c * 256;
        const int row = task & 127;
        const int ob = task >> 7;                 // 0..7
        const int hh = ob >> 2, gg = ob & 3;
        const int w = row >> 5;
        const int r5 = row & 31;
        const int rt = r5 >> 4;
        const int ll = gg * 16 + (row & 15);
        float part = 0.f;
        short8 H, L;
#pragma unroll
        for (int j = 0; j < 8; ++j) {
            const float x = in[(size_t)(ob * 8 + j) * NR + rowBase + row];
            const unsigned short hb = bf16rne(x);
            H[j] = (short)hb;
            L[j] = (short)bf16rne(x - bf16tof(hb));
            part = fmaf(x, x, part);
        }
        xs[w][rt * 4 + hh][ll] = H;
        xs[w][rt * 4 + 2 + hh][ll] = L;
        atomicAdd(&rx2s[row], part);
    }
    __syncthreads();   // full drain: phase-1 LDS visible, stage(0) landed

    // xq resident (8 short8 = 32 VGPR, proven-kept since R25).
    short8 xq[2][4];
#pragma unroll
    for (int rt = 0; rt < 2; ++rt)
#pragma unroll
        for (int q = 0; q < 4; ++q)
            xq[rt][q] = xs[wid][rt * 4 + q][l];

    float best[2]  = {3.4e38f, 3.4e38f};
    float best2[2] = {3.4e38f, 3.4e38f};
    int bestk[2] = {0, 0};

    for (int t = 0; t < 64; ++t) {
        const int cur = t & 1;
        if (t < 63) {
            const short8* s_ = cbt + (size_t)(t + 1) * 512;
            GLOAD_LDS16(s_ + wid * 64 + l, &lbuf[cur ^ 1][wid * 64]);
            GLOAD_LDS16(s_ + (wid + 4) * 64 + l, &lbuf[cur ^ 1][(wid + 4) * 64]);
            asm volatile("s_waitcnt vmcnt(2)" ::: "memory"); // tile t landed
        } else {
            asm volatile("s_waitcnt vmcnt(0)" ::: "memory");
        }
        __builtin_amdgcn_s_barrier();              // tile t ready (all waves)

        const short8 b0 = lbuf[cur][0 * 64 + l], b1 = lbuf[cur][1 * 64 + l],
                     b2 = lbuf[cur][2 * 64 + l], b3 = lbuf[cur][3 * 64 + l];
        const f32x4 e4 = __builtin_bit_cast(f32x4, lbuf[cur][256 + l]);
#pragma unroll
        for (int rt = 0; rt < 2; ++rt) {
            f32x4 acc = e4;
            acc = __builtin_amdgcn_mfma_f32_16x16x32_bf16(b0, xq[rt][0], acc, 0, 0, 0);
            acc = __builtin_amdgcn_mfma_f32_16x16x32_bf16(b1, xq[rt][1], acc, 0, 0, 0);
            acc = __builtin_amdgcn_mfma_f32_16x16x32_bf16(b2, xq[rt][0], acc, 0, 0, 0);
            acc = __builtin_amdgcn_mfma_f32_16x16x32_bf16(b3, xq[rt][1], acc, 0, 0, 0);
            acc = __builtin_amdgcn_mfma_f32_16x16x32_bf16(b0, xq[rt][2], acc, 0, 0, 0);
            acc = __builtin_amdgcn_mfma_f32_16x16x32_bf16(b1, xq[rt][3], acc, 0, 0, 0);
#pragma unroll
            for (int r = 0; r < 4; ++r) {
                const float v = acc[r];
                const int k = t * 16 + g * 4 + r;
                best2[rt] = fminf(fmaxf(v, best[rt]), best2[rt]);  // med3
                const bool c = v < best[rt];
                bestk[rt] = c ? k : bestk[rt];
                best[rt]  = fminf(v, best[rt]);
            }
        }
        __builtin_amdgcn_s_barrier();              // done reading lbuf[cur]
    }

    // Finalize: g-merge via shfl butterfly (every lane gets its col's
    // result); lanes l<16 own rows wid*32 + rt*16 + l.
    double d2 = 0.0;
#pragma unroll
    for (int rt = 0; rt < 2; ++rt) {
        float b = best[rt], b2 = best2[rt]; int k = bestk[rt];
#pragma unroll
        for (int sh = 16; sh <= 32; sh <<= 1) {
            const float ob  = __shfl_xor(b, sh, 64);
            const float ob2 = __shfl_xor(b2, sh, 64);
            const int   ok  = __shfl_xor(k, sh, 64);
            if (ob < b || (ob == b && ok < k)) { b2 = fminf(b, ob2); k = ok; b = ob; }
            else b2 = fminf(b2, ob);
        }
        if (l < 16) {
            const int lrow = wid * 32 + rt * 16 + l;
            const int row = rowBase + lrow;
            idx[row] = k;
            fidx[lrow] = k;
            atomicAdd(&counts[k], 1u);
            if (b2 - b < GAP1) {
                const unsigned p = atomicAdd(flagcnt, 1u);
                flaglist[p] = (unsigned)row;
            }
            d2 += (double)b + (double)rx2s[lrow];
        }
    }
#pragma unroll
    for (int off = 32; off > 0; off >>= 1) d2 += __shfl_down(d2, off, 64);
    if (l == 0) pblk[blockIdx.x * 4 + wid] = d2;
    __syncthreads();

    // Phase 4: gather; thread (row=tid&127, e0=tid>>7 in 0..1), 32 e each.
    {
        const int row = tid & 127;
        const int e0 = tid >> 7;                  // 0..1
        const int k = fidx[row];
        const float4* c4 = (const float4*)(cb + (size_t)k * ED + e0 * 32);
#pragma unroll
        for (int j = 0; j < 8; ++j) {
            const float4 v = c4[j];
            qout[(size_t)(e0 * 32 + j * 4 + 0) * NR + rowBase + row] = v.x;
            qout[(size_t)(e0 * 32 + j * 4 + 1) * NR + rowBase + row] = v.y;
            qout[(size_t)(e0 * 32 + j * 4 + 2) * NR + rowBase + row] = v.z;
            qout[(size_t)(e0 * 32 + j * 4 + 3) * NR + rowBase + row] = v.w;
        }
    }
}

// fp64 exact argmin for flagged rows; one wave per row; plain kernel (no
// fence/ticket -- R25-R27 lesson). Fixes idx/counts/qout on change.
__global__ __launch_bounds__(256) void k_exact64(
        const float* __restrict__ in, const float* __restrict__ cb,
        int* __restrict__ idx, float* __restrict__ qout,
        unsigned* __restrict__ counts,
        const unsigned* __restrict__ flagcnt, const unsigned* __restrict__ flaglist) {
    const unsigned nf = *flagcnt;
    const int l = threadIdx.x & 63;
    const unsigned wave = blockIdx.x * 4u + (unsigned)(threadIdx.x >> 6);
    const unsigned nwave = gridDim.x * 4u;
    for (unsigned i = wave; i < nf; i += nwave) {
        const int row = (int)flaglist[i];
        float x[ED];
#pragma unroll
        for (int e = 0; e < ED; ++e) x[e] = in[(size_t)e * NR + row];
        double best = 1e300; int bestk = 0;
        for (int ci = 0; ci < 16; ++ci) {
            const int k = ci * 64 + l;              // ascending k per lane
            const float* c = cb + (size_t)k * ED;
            double s = 0.0, e2 = 0.0;
            for (int e = 0; e < ED; ++e) {
                const double cv = (double)c[e];
                e2 = fma(cv, cv, e2);
                s  = fma(cv, (double)x[e], s);
            }
            const double t = fma(-2.0, s, e2);
            if (t < best) { best = t; bestk = k; }
        }
        for (int sh = 1; sh < 64; sh <<= 1) {
            const double ob = __shfl_xor(best, sh, 64);
            const int   ok  = __shfl_xor(bestk, sh, 64);
            if (ob < best || (ob == best && ok < bestk)) { best = ob; bestk = ok; }
        }
        const int old = idx[row];                  // same addr all lanes
        if (bestk != old) {
            if (l == 0) {
                idx[row] = bestk;
                atomicSub(&counts[old], 1u);
                atomicAdd(&counts[bestk], 1u);
            }
            qout[(size_t)l * NR + row] = cb[(size_t)bestk * ED + l];
        }
    }
}

// Scalars: entropy from final counts + SSE from 2048 per-wave partials.
__global__ __launch_bounds__(1024) void k_final(const unsigned* __restrict__ counts,
        const double* __restrict__ pblk, float* __restrict__ out) {
    __shared__ double redE[16], redS[16];
    const int tid = threadIdx.x;
    const double p = (double)counts[tid] * (1.0 / 65536.0);
    double term = p * log(p + 1e-10);
    double s = pblk[tid] + pblk[tid + 1024];
#pragma unroll
    for (int off = 32; off > 0; off >>= 1) {
        term += __shfl_down(term, off, 64);
        s    += __shfl_down(s,    off, 64);
    }
    if ((tid & 63) == 0) { redE[tid >> 6] = term; redS[tid >> 6] = s; }
    __syncthreads();
    if (tid == 0) {
        double e = 0.0, ss = 0.0;
        for (int i = 0; i < 16; ++i) { e += redE[i]; ss += redS[i]; }
        out[1 + NE] = (float)exp(-e);                 // perplexity
        const double m = ss * (1.0 / 4194304.0);      // mean((q-x)^2)
        out[0] = (float)(1.25 * m);                   // (1+beta)*m
    }
}

extern "C" void kernel_launch(void* const* d_in, const int* in_sizes, int n_in,
                              void* d_out, int out_size, void* d_ws, size_t ws_size,
                              hipStream_t stream) {
    (void)in_sizes; (void)n_in; (void)out_size; (void)ws_size;
    const float* in = (const float*)d_in[0];
    const float* cb = (const float*)d_in[1];
    float* out = (float*)d_out;

    // ws layout (dword offsets), strictly disjoint -- audited end-to-end:
    //  [0,1024) counts | [1024] flagcnt
    //  [2048,133120)   cbt: 64 tiles x 512 short8 x 4 dw = 131072 dw (512KB)
    //  [133120,198656) idx (65536)
    //  [198656,264192) flaglist (65536)
    //  [264192,268288) pblk: 2048 f64 (byte 1056768, 8B-aligned)
    unsigned* counts   = (unsigned*)d_ws;
    unsigned* flagcnt  = (unsigned*)d_ws + 1024;
    short8*   cbt      = (short8*)((float*)d_ws + 2048);
    int*      idx      = (int*)d_ws + 133120;
    unsigned* flaglist = (unsigned*)d_ws + 198656;
    double*   pblk     = (double*)((char*)d_ws + 1056768);

    hipLaunchKernelGGL(k_pack,    dim3(80),  dim3(256),  0, stream,
                       cb, cbt, counts, flagcnt);
    hipLaunchKernelGGL(k_argmin,  dim3(512), dim3(256),  0, stream,
                       in, cbt, cb, idx, out + 1, counts, flagcnt, flaglist, pblk);
    hipLaunchKernelGGL(k_exact64, dim3(256), dim3(256),  0, stream,
                       in, cb, idx, out + 1, counts, flagcnt, flaglist);
    hipLaunchKernelGGL(k_final,   dim3(1),   dim3(1024), 0, stream,
                       counts, pblk, out);
}

// Round 30
// 79.257 us; speedup vs baseline: 1.3811x; 1.3811x over previous
//
#include <hip/hip_runtime.h>

// VQ-VAE VectorQuantizer fwd. K=1024, E=64, T=1024, B=64 (N=65536).
// FINAL (R30 = R24, best measured 79.4us): 2-tier argmin.
// Tier-1: 3-term bf16-split MFMA (ch*xh + cl*xh + ch*xl; err ~1e-7,
// GAP1=6e-6) -> tier-2 fp64 exact re-resolve for flagged rows.
// Scores t = ||c||^2 - 2 x.c; codebook pre-scaled by -2, ||c||^2 in C-init.
// MFMA: A = codebook frag, B = x frag -> D(lane l, reg r) =
// score(code = t*16 + (l>>4)*4 + r, row = base + (l&15)).
// Plateau notes (R12-R29): per-wave private K-quarter streams sit at
// argmin ~46us regardless of rows/wave (traffic-independent -> issue/
// latency-structure-bound); LDS-staged lockstep pipelines regress (barrier
// cost > L2 re-read saved); device-scope fences in multi-block kernels
// serialize L2 drains (~0.4us/block) -- keep final reduce a separate
// 1-block launch.

#define KC 1024
#define ED 64
#define NR 65536
#define NE (NR * ED)
#define GAP1 6e-6f

typedef __attribute__((ext_vector_type(8))) short short8;
typedef __attribute__((ext_vector_type(4))) float f32x4;

__device__ __forceinline__ unsigned short bf16rne(float f) {
    unsigned u = __builtin_bit_cast(unsigned, f);
    return (unsigned short)((u + 0x7fffu + ((u >> 16) & 1u)) >> 16);
}
__device__ __forceinline__ float bf16tof(unsigned short h) {
    return __builtin_bit_cast(float, (unsigned)h << 16);
}

// Pack compact tile records (stride 320 short8 = 5KB) + zero counters.
// Record t: j=0,1 = ch (hi bf16 of -2*c) for e in [0,32),[32,64); j=2,3 =
// cl (lo residual); elem (g=l>>4,r) <-> e = (j&1)*32 + g*8 + r (same
// bijection as the x fragments); j=4: f32x4 ||c||^2 (reg r <-> code
// t*16+(l>>4)*4+r) bitcast short8.
__global__ __launch_bounds__(256) void k_pack(const float* __restrict__ cb,
        short8* __restrict__ cbt, unsigned* __restrict__ counts,
        unsigned* __restrict__ flagcnt) {
    const int u = blockIdx.x * 256 + threadIdx.x;
    if (u < 1024) counts[u] = 0u;
    if (u == 1024) *flagcnt = 0u;
    if (u >= 64 * 5 * 64) return;
    const int t = u / 320, rem = u % 320, j = rem / 64, l = rem % 64;
    const int g = l >> 4;
    if (j < 4) {
        const int code = t * 16 + (l & 15);
        const float* c = cb + (size_t)code * ED;
        const bool lo = (j >= 2);
        short8 o;
#pragma unroll
        for (int r = 0; r < 8; ++r) {
            const int e = (j & 1) * 32 + g * 8 + r;
            const float m2 = -2.f * c[e];
            const unsigned short h = bf16rne(m2);
            o[r] = lo ? (short)bf16rne(m2 - bf16tof(h)) : (short)h;
        }
        cbt[u] = o;
    } else {
        f32x4 o;
#pragma unroll
        for (int r = 0; r < 4; ++r) {
            const float4* c4 = (const float4*)(cb + (size_t)(t * 16 + g * 4 + r) * ED);
            float s0 = 0.f, s1 = 0.f, s2 = 0.f, s3 = 0.f;
#pragma unroll
            for (int i = 0; i < 16; ++i) {
                const float4 c = c4[i];
                s0 = fmaf(c.x, c.x, s0); s1 = fmaf(c.y, c.y, s1);
                s2 = fmaf(c.z, c.z, s2); s3 = fmaf(c.w, c.w, s3);
            }
            o[r] = (s0 + s1) + (s2 + s3);
        }
        cbt[u] = __builtin_bit_cast(short8, o);
    }
}

// 1024 blocks x 256 thr (4 waves = 4 K-quarters), 64 rows/block, exactly
// 4 blocks/CU. Phase 1: cooperative x -> bf16 hi/lo frags into LDS +
// ||x||^2 partials. Phase 2: wave kh scans tiles [kh*16,+16): 5 loads +
// 24 MFMA + med3 min-track (b0,b1 reused for xl terms). Phase 3: shfl
// g-merge; wave 0 merges kh slices (ascending k tie-break), writes
// idx/fidx/histogram/flag/SSE (d^2 = best + ||x||^2). Phase 4: gather.
__global__ __launch_bounds__(256) void k_argmin(
        const float* __restrict__ in, const short8* __restrict__ cbt,
        const float* __restrict__ cb, int* __restrict__ idx,
        float* __restrict__ qout, unsigned* __restrict__ counts,
        unsigned* __restrict__ flagcnt, unsigned* __restrict__ flaglist,
        double* __restrict__ pblk) {
    __shared__ short8 xs[16][64];                 // 16 KB
    __shared__ float rx2p[4][64];                 // 1 KB
    __shared__ float sb[4][4][16], sb2[4][4][16];
    __shared__ int   sk[4][4][16];                // 3 KB
    __shared__ int   fidx[64];

    const int tid = threadIdx.x;
    const int l = tid & 63;
    const int wid = tid >> 6;                     // 0..3 == kh
    const int g = l >> 4;
    const int col = l & 15;
    const int rowBase = blockIdx.x * 64;

    // Phase 1: thread (row=tid&63, ob=tid>>6) converts e in {hh*32+ob*8+j}
    // (16 elems) of its row; ll = ob*16 + (row&15), slot = rt*4 + hh (+2 lo).
    {
        const int row = tid & 63;
        const int ob = tid >> 6;                  // 0..3 (== g of the frag)
        const int rt = row >> 4;
        const int ll = ob * 16 + (row & 15);
        float part = 0.f;
#pragma unroll
        for (int hh = 0; hh < 2; ++hh) {
            short8 H, L;
#pragma unroll
            for (int j = 0; j < 8; ++j) {
                const float x = in[(size_t)(hh * 32 + ob * 8 + j) * NR + rowBase + row];
                const unsigned short hb = bf16rne(x);
                H[j] = (short)hb;
                L[j] = (short)bf16rne(x - bf16tof(hb));
                part = fmaf(x, x, part);
            }
            xs[rt * 4 + hh][ll] = H;
            xs[rt * 4 + 2 + hh][ll] = L;
        }
        rx2p[ob][row] = part;
    }
    __syncthreads();

    // Phase 2: all 16 x-frags staged, simple tile loop.
    const int kh = wid;
    short8 xq[4][4];
#pragma unroll
    for (int rt = 0; rt < 4; ++rt)
#pragma unroll
        for (int q = 0; q < 4; ++q)
            xq[rt][q] = xs[rt * 4 + q][l];

    float best[4]  = {3.4e38f, 3.4e38f, 3.4e38f, 3.4e38f};
    float best2[4] = {3.4e38f, 3.4e38f, 3.4e38f, 3.4e38f};
    int bestk[4] = {0, 0, 0, 0};

#pragma unroll 2
    for (int tt = 0; tt < 16; ++tt) {
        const int t = kh * 16 + tt;
        const short8* bp = cbt + (size_t)t * 320 + l;
        const short8 b0 = bp[0], b1 = bp[64], b2 = bp[128], b3 = bp[192];
        const f32x4 e4 = __builtin_bit_cast(f32x4, bp[256]);
#pragma unroll
        for (int rt = 0; rt < 4; ++rt) {
            f32x4 acc = e4;
            acc = __builtin_amdgcn_mfma_f32_16x16x32_bf16(b0, xq[rt][0], acc, 0, 0, 0);
            acc = __builtin_amdgcn_mfma_f32_16x16x32_bf16(b1, xq[rt][1], acc, 0, 0, 0);
            acc = __builtin_amdgcn_mfma_f32_16x16x32_bf16(b2, xq[rt][0], acc, 0, 0, 0);
            acc = __builtin_amdgcn_mfma_f32_16x16x32_bf16(b3, xq[rt][1], acc, 0, 0, 0);
            acc = __builtin_amdgcn_mfma_f32_16x16x32_bf16(b0, xq[rt][2], acc, 0, 0, 0);
            acc = __builtin_amdgcn_mfma_f32_16x16x32_bf16(b1, xq[rt][3], acc, 0, 0, 0);
#pragma unroll
            for (int r = 0; r < 4; ++r) {
                const float v = acc[r];
                const int k = t * 16 + g * 4 + r;
                best2[rt] = fminf(fmaxf(v, best[rt]), best2[rt]);  // med3
                const bool c = v < best[rt];
                bestk[rt] = c ? k : bestk[rt];
                best[rt]  = fminf(v, best[rt]);
            }
        }
    }

    // Phase 3a: intra-wave g-merge; g==0 writes per-kh partials.
#pragma unroll
    for (int rt = 0; rt < 4; ++rt) {
        float b = best[rt], b2 = best2[rt]; int k = bestk[rt];
#pragma unroll
        for (int sh = 16; sh <= 32; sh <<= 1) {
            const float ob  = __shfl_xor(b, sh, 64);
            const float ob2 = __shfl_xor(b2, sh, 64);
            const int   ok  = __shfl_xor(k, sh, 64);
            if (ob < b || (ob == b && ok < k)) { b2 = fminf(b, ob2); k = ok; b = ob; }
            else b2 = fminf(b2, ob);
        }
        if (g == 0) { sb[wid][rt][col] = b; sb2[wid][rt][col] = b2; sk[wid][rt][col] = k; }
    }
    __syncthreads();

    // Phase 3b: wave 0 merges the 4 kh slices; lane l owns row rt*16+c2.
    if (wid == 0) {
        const int rt = l >> 4, c2 = l & 15;
        float b = sb[0][rt][c2], b2 = sb2[0][rt][c2]; int k = sk[0][rt][c2];
#pragma unroll
        for (int s = 1; s < 4; ++s) {              // ascending k ranges
            const float ob = sb[s][rt][c2], ob2 = sb2[s][rt][c2];
            const int ok = sk[s][rt][c2];
            if (ob < b || (ob == b && ok < k)) { b2 = fminf(b, ob2); k = ok; b = ob; }
            else b2 = fminf(b2, ob);
        }
        const int lrow = rt * 16 + c2;
        const int row = rowBase + lrow;
        idx[row] = k;
        fidx[lrow] = k;
        atomicAdd(&counts[k], 1u);
        if (b2 - b < GAP1) {
            const unsigned p = atomicAdd(flagcnt, 1u);
            flaglist[p] = (unsigned)row;
        }
        double d2 = (double)b + (double)((rx2p[0][lrow] + rx2p[1][lrow])
                                       + (rx2p[2][lrow] + rx2p[3][lrow]));
#pragma unroll
        for (int off = 32; off > 0; off >>= 1) d2 += __shfl_down(d2, off, 64);
        if (l == 0) pblk[blockIdx.x] = d2;
    }
    __syncthreads();

    // Phase 4: cooperative gather; lanes cover 64 consecutive rows per e.
    {
        const int row = tid & 63;
        const int e0 = tid >> 6;                  // 0..3
        const int k = fidx[row];
        const float4* c4 = (const float4*)(cb + (size_t)k * ED + e0 * 16);
#pragma unroll
        for (int j = 0; j < 4; ++j) {
            const float4 v = c4[j];
            qout[(size_t)(e0 * 16 + j * 4 + 0) * NR + rowBase + row] = v.x;
            qout[(size_t)(e0 * 16 + j * 4 + 1) * NR + rowBase + row] = v.y;
            qout[(size_t)(e0 * 16 + j * 4 + 2) * NR + rowBase + row] = v.z;
            qout[(size_t)(e0 * 16 + j * 4 + 3) * NR + rowBase + row] = v.w;
        }
    }
}

// fp64 exact argmin for flagged rows; one wave per row; adjusts histogram
// and rewrites the row's qout column on change. Plain kernel (no fence).
__global__ __launch_bounds__(256) void k_exact64(
        const float* __restrict__ in, const float* __restrict__ cb,
        int* __restrict__ idx, float* __restrict__ qout,
        unsigned* __restrict__ counts,
        const unsigned* __restrict__ flagcnt, const unsigned* __restrict__ flaglist) {
    const unsigned nf = *flagcnt;
    const int l = threadIdx.x & 63;
    const unsigned wave = blockIdx.x * 4u + (unsigned)(threadIdx.x >> 6);
    const unsigned nwave = gridDim.x * 4u;
    for (unsigned i = wave; i < nf; i += nwave) {
        const int row = (int)flaglist[i];
        float x[ED];
#pragma unroll
        for (int e = 0; e < ED; ++e) x[e] = in[(size_t)e * NR + row];
        double best = 1e300; int bestk = 0;
        for (int ci = 0; ci < 16; ++ci) {
            const int k = ci * 64 + l;              // ascending k per lane
            const float* c = cb + (size_t)k * ED;
            double s = 0.0, e2 = 0.0;
            for (int e = 0; e < ED; ++e) {
                const double cv = (double)c[e];
                e2 = fma(cv, cv, e2);
                s  = fma(cv, (double)x[e], s);
            }
            const double t = fma(-2.0, s, e2);
            if (t < best) { best = t; bestk = k; }
        }
        for (int sh = 1; sh < 64; sh <<= 1) {
            const double ob = __shfl_xor(best, sh, 64);
            const int   ok  = __shfl_xor(bestk, sh, 64);
            if (ob < best || (ob == best && ok < bestk)) { best = ob; bestk = ok; }
        }
        const int old = idx[row];                  // same addr all lanes
        if (bestk != old) {
            if (l == 0) {
                idx[row] = bestk;
                atomicSub(&counts[old], 1u);
                atomicAdd(&counts[bestk], 1u);
            }
            qout[(size_t)l * NR + row] = cb[(size_t)bestk * ED + l];
        }
    }
}

// Scalars: entropy from final counts + SSE from 1024 per-block partials
// (fixed-order tree -> deterministic).
__global__ __launch_bounds__(1024) void k_final(const unsigned* __restrict__ counts,
        const double* __restrict__ pblk, float* __restrict__ out) {
    __shared__ double redE[16], redS[16];
    const int tid = threadIdx.x;
    const double p = (double)counts[tid] * (1.0 / 65536.0);
    double term = p * log(p + 1e-10);
    double s = pblk[tid];
#pragma unroll
    for (int off = 32; off > 0; off >>= 1) {
        term += __shfl_down(term, off, 64);
        s    += __shfl_down(s,    off, 64);
    }
    if ((tid & 63) == 0) { redE[tid >> 6] = term; redS[tid >> 6] = s; }
    __syncthreads();
    if (tid == 0) {
        double e = 0.0, ss = 0.0;
        for (int i = 0; i < 16; ++i) { e += redE[i]; ss += redS[i]; }
        out[1 + NE] = (float)exp(-e);                 // perplexity
        const double m = ss * (1.0 / 4194304.0);      // mean((q-x)^2)
        out[0] = (float)(1.25 * m);                   // (1+beta)*m
    }
}

extern "C" void kernel_launch(void* const* d_in, const int* in_sizes, int n_in,
                              void* d_out, int out_size, void* d_ws, size_t ws_size,
                              hipStream_t stream) {
    (void)in_sizes; (void)n_in; (void)out_size; (void)ws_size;
    const float* in = (const float*)d_in[0];
    const float* cb = (const float*)d_in[1];
    float* out = (float*)d_out;

    // ws layout (dword offsets), strictly disjoint -- audited end-to-end:
    //  [0,1024) counts | [1024] flagcnt
    //  [2048,83968)    cbt: 64 tiles x 320 short8 x 4 dw = 81920 dw (320KB)
    //  [83968,149504)  idx (65536)
    //  [149504,215040) flaglist (65536)
    //  [215040,217088) pblk: 1024 f64 (byte 860160, 8B-aligned)
    unsigned* counts   = (unsigned*)d_ws;
    unsigned* flagcnt  = (unsigned*)d_ws + 1024;
    short8*   cbt      = (short8*)((float*)d_ws + 2048);
    int*      idx      = (int*)d_ws + 83968;
    unsigned* flaglist = (unsigned*)d_ws + 149504;
    double*   pblk     = (double*)((char*)d_ws + 860160);

    hipLaunchKernelGGL(k_pack,    dim3(80),   dim3(256),  0, stream,
                       cb, cbt, counts, flagcnt);
    hipLaunchKernelGGL(k_argmin,  dim3(1024), dim3(256),  0, stream,
                       in, cbt, cb, idx, out + 1, counts, flagcnt, flaglist, pblk);
    hipLaunchKernelGGL(k_exact64, dim3(128),  dim3(256),  0, stream,
                       in, cb, idx, out + 1, counts, flagcnt, flaglist);
    hipLaunchKernelGGL(k_final,   dim3(1),    dim3(1024), 0, stream,
                       counts, pblk, out);
}